// Round 5
// baseline (445.964 us; speedup 1.0000x reference)
//
#include <hip/hip_runtime.h>

// SNN forward scan (LIF, Heaviside forward). T=2048, B=64, F=512.
// W is block-diagonal with 2x2 blocks -> ff[f] = W[f,f0]*x[f0]+W[f,f0+1]*x[f0+1],
// f0 = f&~1; all other dot terms are exact fp32 zeros (bitwise identical).
//
// R5: back to the PROVEN R1 structure (producer/consumer LDS designs failed
// twice with a no-output signature). Fix R1's measured deficit instead:
//   - R1 ran 2.5 TB/s because burst-prefetch fills the vmem queue then drains
//     it to empty each chunk (Little's law: avg in-flight ~ half) AND its
//     VGPR_Count=64 proved the buffers spilled (no min-waves hint).
//   - Now: prefetch distance 3 (CHUNK=16, 4 rotating register buffers, outer
//     loop unrolled x4 so all indices are static), 512 blocks x 64 threads =
//     2 waves/CU = two vmem queues, __launch_bounds__(64,2) -> <=256 VGPRs
//     (room for buffers, and 2 blocks/CU guaranteed co-resident).
// Numerics: __fmul_rn/__fadd_rn forbid FMA contraction; rounding sequence
// matches numpy bitwise (Heaviside output: one flipped spike = absmax 1.0).

constexpr int T_STEPS = 2048;
constexpr int B_DIM   = 64;
constexpr int F_DIM   = 512;
constexpr int BF      = B_DIM * F_DIM;       // 32768 elements per timestep
constexpr int CHUNK   = 16;                  // t-steps per register buffer
constexpr int NCHUNK  = T_STEPS / CHUNK;     // 128 (multiple of 4)

__global__ __launch_bounds__(64, 2) void snn_scan_kernel(
    const float* __restrict__ x,
    const float* __restrict__ W,
    const float* __restrict__ leak_i,
    const float* __restrict__ leak_v,
    const float* __restrict__ thresh,
    float* __restrict__ out) {

    const int g = blockIdx.x * 64 + threadIdx.x;   // g = b*F + f
    const int f  = g & (F_DIM - 1);
    const int f0 = f & ~1;

    // 2x2 block weights for this output row f (loop-invariant).
    const float w_even = W[f * F_DIM + f0];        // coeff on x[f0]
    const float w_odd  = W[f * F_DIM + f0 + 1];    // coeff on x[f0+1]
    const float li = leak_i[f];
    const float lv = leak_v[f];
    const float th = thresh[f];
    const bool  is_even = ((f & 1) == 0);

    float i_s = 0.0f, v_s = 0.0f, z_s = 0.0f;

    const float* xp = x + g;
    float*       op = out + g;

    float bufA[CHUNK], bufB[CHUNK], bufC[CHUNK], bufD[CHUNK];

    auto load_chunk = [&](int c, float (&buf)[CHUNK]) {
        const float* p = xp + (size_t)c * (CHUNK * BF);
        #pragma unroll
        for (int j = 0; j < CHUNK; ++j) buf[j] = p[(size_t)j * BF];
    };

    auto process_chunk = [&](int c, float (&buf)[CHUNK]) {
        float* o = op + (size_t)c * (CHUNK * BF);
        #pragma unroll
        for (int j = 0; j < CHUNK; ++j) {
            const float xo = buf[j];
            const float xpair = __shfl_xor(xo, 1, 64);   // partner f^1
            const float xa = is_even ? xo : xpair;       // x at even f of block
            const float xb = is_even ? xpair : xo;       // x at odd  f of block
            const float ff = __fadd_rn(__fmul_rn(w_even, xa), __fmul_rn(w_odd, xb));
            i_s = __fadd_rn(__fmul_rn(li, i_s), ff);
            float vmul = __fmul_rn(lv, v_s);
            vmul = (z_s > 0.0f) ? 0.0f : vmul;           // reset-to-zero on spike
            v_s = __fadd_rn(vmul, i_s);
            z_s = (v_s > th) ? 1.0f : 0.0f;              // heaviside(v - thresh)
            o[(size_t)j * BF] = z_s;
        }
    };

    // Prefetch-distance-3 rotating pipeline; outer loop unrolled x4 so every
    // buffer reference is a distinct named array (registers, no scratch).
    load_chunk(0, bufA);
    load_chunk(1, bufB);
    load_chunk(2, bufC);
    for (int c = 0; c < NCHUNK; c += 4) {
        if (c + 3 < NCHUNK) load_chunk(c + 3, bufD);
        process_chunk(c, bufA);
        if (c + 4 < NCHUNK) load_chunk(c + 4, bufA);
        process_chunk(c + 1, bufB);
        if (c + 5 < NCHUNK) load_chunk(c + 5, bufB);
        process_chunk(c + 2, bufC);
        if (c + 6 < NCHUNK) load_chunk(c + 6, bufC);
        process_chunk(c + 3, bufD);
    }
}

extern "C" void kernel_launch(void* const* d_in, const int* in_sizes, int n_in,
                              void* d_out, int out_size, void* d_ws, size_t ws_size,
                              hipStream_t stream) {
    const float* x      = (const float*)d_in[0];
    const float* W      = (const float*)d_in[1];
    const float* leak_i = (const float*)d_in[2];
    const float* leak_v = (const float*)d_in[3];
    const float* thresh = (const float*)d_in[4];
    float* out = (float*)d_out;

    // 32768 column-threads; 512 blocks x 64 -> 2 waves/CU on 256 CUs.
    snn_scan_kernel<<<dim3(BF / 64), dim3(64), 0, stream>>>(
        x, W, leak_i, leak_v, thresh, out);
}

// Round 6
// 436.211 us; speedup vs baseline: 1.0224x; 1.0224x over previous
//
#include <hip/hip_runtime.h>

// SNN forward scan (LIF, Heaviside forward). T=2048, B=64, F=512.
// W is block-diagonal with 2x2 blocks -> per feature pair (f0,f0+1) the
// synapse is a 2x2 matvec; all other dot terms are exact fp32 zeros, so this
// is bitwise identical to the reference's full dot product.
//
// R6 theory: R1/R2/R5 all plateau at ~2.5-2.8 TB/s despite wildly different
// nominal prefetch depth -> effective in-flight vmem ENTRIES per wave are
// capped (~8; loads+stores share the queue). Lever = bytes per entry:
//   - float2 per thread (one 2x2 block; bit-exact proven in R2, kills the
//     per-step DS shfl) -> 8 B loads AND 8 B stores.
//   - R5's proven rotating distance-3 register pipeline (R2 only burst-loaded).
//   - nontemporal loads/stores: x and out are stream-once; nt avoids
//     allocating in the poison-dirtied L2/L3 and improves write-combining.
// Structure stays 64-thread single-wave blocks (3-for-3 passing; both
// 128-thread designs failed unexplained): 256 blocks x 64 = 1 wave/CU.
// Numerics: __fmul_rn/__fadd_rn forbid FMA contraction; rounding sequence
// matches numpy bitwise (Heaviside output: one flipped spike = absmax 1.0).

typedef float v2f __attribute__((ext_vector_type(2)));

constexpr int T_STEPS = 2048;
constexpr int B_DIM   = 64;
constexpr int F_DIM   = 512;
constexpr int BF      = B_DIM * F_DIM;       // 32768 floats per timestep
constexpr int NPAIR   = BF / 2;              // 16384 float2 pairs per timestep
constexpr int CHUNK   = 16;                  // t-steps per register buffer
constexpr int NCHUNK  = T_STEPS / CHUNK;     // 128 (multiple of 4)

__global__ __launch_bounds__(64, 2) void snn_scan_kernel(
    const float* __restrict__ x,
    const float* __restrict__ W,
    const float* __restrict__ leak_i,
    const float* __restrict__ leak_v,
    const float* __restrict__ thresh,
    float* __restrict__ out) {

    const int p  = blockIdx.x * 64 + threadIdx.x;  // pair index
    const int e  = 2 * p;                          // flat b*F + f0 (even)
    const int f0 = e & (F_DIM - 1);                // even feature of the 2x2 block

    // 2x2 block of W for rows f0, f0+1 (loop-invariant).
    const float w00 = W[(size_t)(f0    ) * F_DIM + f0    ];
    const float w01 = W[(size_t)(f0    ) * F_DIM + f0 + 1];
    const float w10 = W[(size_t)(f0 + 1) * F_DIM + f0    ];
    const float w11 = W[(size_t)(f0 + 1) * F_DIM + f0 + 1];
    const float li0 = leak_i[f0], li1 = leak_i[f0 + 1];
    const float lv0 = leak_v[f0], lv1 = leak_v[f0 + 1];
    const float th0 = thresh[f0], th1 = thresh[f0 + 1];

    float i0 = 0.0f, v0 = 0.0f, z0 = 0.0f;   // even-f neuron state
    float i1 = 0.0f, v1 = 0.0f, z1 = 0.0f;   // odd-f neuron state

    const v2f* xp = (const v2f*)(x + e);     // stride NPAIR v2f per timestep
    v2f*       op = (v2f*)(out + e);

    v2f bufA[CHUNK], bufB[CHUNK], bufC[CHUNK], bufD[CHUNK];

    auto load_chunk = [&](int c, v2f (&buf)[CHUNK]) {
        const v2f* ptr = xp + (size_t)c * (CHUNK * NPAIR);
        #pragma unroll
        for (int j = 0; j < CHUNK; ++j)
            buf[j] = __builtin_nontemporal_load(ptr + (size_t)j * NPAIR);
    };

    auto process_chunk = [&](int c, v2f (&buf)[CHUNK]) {
        v2f* o = op + (size_t)c * (CHUNK * NPAIR);
        #pragma unroll
        for (int j = 0; j < CHUNK; ++j) {
            const float xe = buf[j].x;
            const float xo = buf[j].y;
            // ff = 2x2 block matvec; remaining dot terms are exact zeros.
            const float ff0 = __fadd_rn(__fmul_rn(w00, xe), __fmul_rn(w01, xo));
            const float ff1 = __fadd_rn(__fmul_rn(w10, xe), __fmul_rn(w11, xo));
            // i_new = leak_i*i + ff
            i0 = __fadd_rn(__fmul_rn(li0, i0), ff0);
            i1 = __fadd_rn(__fmul_rn(li1, i1), ff1);
            // v_new = (leak_v*v)*(1-z) + i_new ; z in {0,1} -> select
            float vm0 = __fmul_rn(lv0, v0);
            float vm1 = __fmul_rn(lv1, v1);
            vm0 = (z0 > 0.0f) ? 0.0f : vm0;
            vm1 = (z1 > 0.0f) ? 0.0f : vm1;
            v0 = __fadd_rn(vm0, i0);
            v1 = __fadd_rn(vm1, i1);
            // z_new = heaviside(v_new - thresh) == (v_new > thresh)
            z0 = (v0 > th0) ? 1.0f : 0.0f;
            z1 = (v1 > th1) ? 1.0f : 0.0f;
            v2f zv; zv.x = z0; zv.y = z1;
            __builtin_nontemporal_store(zv, o + (size_t)j * NPAIR);
        }
    };

    // Rotating distance-3 pipeline; outer loop unrolled x4 so every buffer
    // reference is a distinct named array (registers, no scratch).
    load_chunk(0, bufA);
    load_chunk(1, bufB);
    load_chunk(2, bufC);
    for (int c = 0; c < NCHUNK; c += 4) {
        if (c + 3 < NCHUNK) load_chunk(c + 3, bufD);
        process_chunk(c, bufA);
        if (c + 4 < NCHUNK) load_chunk(c + 4, bufA);
        process_chunk(c + 1, bufB);
        if (c + 5 < NCHUNK) load_chunk(c + 5, bufB);
        process_chunk(c + 2, bufC);
        if (c + 6 < NCHUNK) load_chunk(c + 6, bufC);
        process_chunk(c + 3, bufD);
    }
}

extern "C" void kernel_launch(void* const* d_in, const int* in_sizes, int n_in,
                              void* d_out, int out_size, void* d_ws, size_t ws_size,
                              hipStream_t stream) {
    const float* x      = (const float*)d_in[0];
    const float* W      = (const float*)d_in[1];
    const float* leak_i = (const float*)d_in[2];
    const float* leak_v = (const float*)d_in[3];
    const float* thresh = (const float*)d_in[4];
    float* out = (float*)d_out;

    // 16384 pair-threads; 256 blocks x 64 -> 1 wave on each of 256 CUs.
    snn_scan_kernel<<<dim3(NPAIR / 64), dim3(64), 0, stream>>>(
        x, W, leak_i, leak_v, thresh, out);
}